// Round 1
// baseline (356.606 us; speedup 1.0000x reference)
//
#include <hip/hip_runtime.h>

#define NN 50000
#define NE 600000
#define DIM 128
#define NB_N 196   // ceil(50000/256)
#define NB_E 2344  // ceil(600000/256)
#define TILES 3125 // 50000/16

typedef unsigned short u16;
typedef unsigned int u32;
typedef __attribute__((ext_vector_type(8))) short bf16x8;
typedef __attribute__((ext_vector_type(4))) float f32x4;

__device__ __forceinline__ u16 f2bf(float f) {
    u32 u = __builtin_bit_cast(u32, f);
    u32 r = (u + 0x7FFFu + ((u >> 16) & 1u)) >> 16;
    return (u16)r;
}
__device__ __forceinline__ float bf2f(u16 h) {
    u32 u = ((u32)h) << 16;
    return __builtin_bit_cast(float, u);
}

// ---- CSR build -------------------------------------------------------------

// deg = 1 (self loop); also detect whether edge_index arrived as int64 or int32.
__global__ __launch_bounds__(256) void k_init(const int* __restrict__ ei,
                                              int* __restrict__ deg,
                                              int* __restrict__ flag) {
    int i = blockIdx.x * 256 + threadIdx.x;
    if (i < NN) deg[i] = 1;
    if (i == 0) {
        int o = 0;
#pragma unroll
        for (int j = 0; j < 16; j++) o |= ei[2 * j + 1];  // int64 => high words all 0
        *flag = (o == 0) ? 1 : 0;
    }
}

__device__ __forceinline__ int load_src(const int* ei, int is64, int e) {
    return is64 ? ei[2 * e] : ei[e];
}
__device__ __forceinline__ int load_dst(const int* ei, int is64, int e) {
    return is64 ? ei[2 * (NE + e)] : ei[NE + e];
}

__global__ __launch_bounds__(256) void k_count(const int* __restrict__ ei,
                                               const int* __restrict__ flag,
                                               int* __restrict__ deg) {
    int e = blockIdx.x * 256 + threadIdx.x;
    if (e >= NE) return;
    int is64 = *flag;
    atomicAdd(&deg[load_dst(ei, is64, e)], 1);
}

__global__ __launch_bounds__(256) void k_dinv(const int* __restrict__ deg,
                                              float* __restrict__ dinv,
                                              int* __restrict__ cursor) {
    int i = blockIdx.x * 256 + threadIdx.x;
    if (i < NN) {
        dinv[i] = rsqrtf((float)deg[i]);
        cursor[i] = 0;
    }
}

// exclusive scan of (deg[i]-1) -> row_ptr, 3-kernel two-level scan
__global__ __launch_bounds__(256) void k_scanA(const int* __restrict__ deg,
                                               int* __restrict__ row_ptr,
                                               int* __restrict__ bsum) {
    __shared__ int buf[256];
    int t = threadIdx.x, i = blockIdx.x * 256 + t;
    int v = (i < NN) ? (deg[i] - 1) : 0;
    buf[t] = v;
    __syncthreads();
    for (int off = 1; off < 256; off <<= 1) {
        int x = (t >= off) ? buf[t - off] : 0;
        __syncthreads();
        buf[t] += x;
        __syncthreads();
    }
    if (i < NN) row_ptr[i] = buf[t] - v;  // block-local exclusive
    if (t == 255) bsum[blockIdx.x] = buf[255];
}

__global__ __launch_bounds__(256) void k_scanB(int* __restrict__ bsum) {
    __shared__ int buf[256];
    int t = threadIdx.x;
    int v = (t < NB_N) ? bsum[t] : 0;
    buf[t] = v;
    __syncthreads();
    for (int off = 1; off < 256; off <<= 1) {
        int x = (t >= off) ? buf[t - off] : 0;
        __syncthreads();
        buf[t] += x;
        __syncthreads();
    }
    bsum[t] = buf[t] - v;  // exclusive block offsets
}

__global__ __launch_bounds__(256) void k_scanC(int* __restrict__ row_ptr,
                                               const int* __restrict__ bsum) {
    int i = blockIdx.x * 256 + threadIdx.x;
    if (i < NN) row_ptr[i] += bsum[i >> 8];
    if (i == 0) row_ptr[NN] = NE;  // total real edges
}

__global__ __launch_bounds__(256) void k_fill(const int* __restrict__ ei,
                                              const int* __restrict__ flag,
                                              const int* __restrict__ row_ptr,
                                              int* __restrict__ cursor,
                                              const float* __restrict__ dinv,
                                              int* __restrict__ csr_src,
                                              float* __restrict__ csr_norm) {
    int e = blockIdx.x * 256 + threadIdx.x;
    if (e >= NE) return;
    int is64 = *flag;
    int s = load_src(ei, is64, e);
    int d = load_dst(ei, is64, e);
    int pos = row_ptr[d] + atomicAdd(&cursor[d], 1);
    csr_src[pos] = s;
    csr_norm[pos] = dinv[s] * dinv[d];
}

// ---- dtype prep ------------------------------------------------------------

// Wt[layer][n][k] = bf16(W[layer][k][n]) : B-operand wants contiguous k per lane
__global__ __launch_bounds__(256) void k_wcast(const float* __restrict__ W0,
                                               const float* __restrict__ W1,
                                               const float* __restrict__ W2,
                                               u16* __restrict__ Wt) {
    int idx = blockIdx.x * 256 + threadIdx.x;  // < 3*16384
    int l = idx >> 14, rem = idx & 16383;
    int n = rem >> 7, k = rem & 127;
    const float* W = (l == 0) ? W0 : ((l == 1) ? W1 : W2);
    Wt[idx] = f2bf(W[k * 128 + n]);
}

__global__ __launch_bounds__(256) void k_xcast(const float* __restrict__ x,
                                               u16* __restrict__ xb) {
    int i = blockIdx.x * 256 + threadIdx.x;  // exactly 1.6M threads, 4 elems each
    float4 v = ((const float4*)x)[i];
    uint2 o;
    o.x = (u32)f2bf(v.x) | ((u32)f2bf(v.y) << 16);
    o.y = (u32)f2bf(v.z) | ((u32)f2bf(v.w) << 16);
    ((uint2*)xb)[i] = o;
}

// ---- GEMM: hw[N,128] = h[N,128] @ W[128,128], bf16 in, bf16 out ------------
// 16x16x32 MFMA. A frag: A[m=lane&15][k=(lane>>4)*8+j]. B frag from Wt[n][k]:
// B[k=(lane>>4)*8+j][n=lane&15]. C/D: col=lane&15, row=(lane>>4)*4+reg.
__global__ __launch_bounds__(256) void k_gemm(const u16* __restrict__ hb,
                                              const u16* __restrict__ Wt,
                                              u16* __restrict__ hwb) {
    int lane = threadIdx.x & 63;
    int tile = blockIdx.x * 4 + (threadIdx.x >> 6);
    if (tile >= TILES) return;
    int r = lane & 15, q = lane >> 4;

    bf16x8 Bf[8][4];
#pragma unroll
    for (int nt = 0; nt < 8; nt++)
#pragma unroll
        for (int kc = 0; kc < 4; kc++)
            Bf[nt][kc] = *(const bf16x8*)(Wt + ((nt * 16 + r) << 7) + kc * 32 + q * 8);

    long rowbase = (long)tile * 16;
    bf16x8 Af[4];
#pragma unroll
    for (int kc = 0; kc < 4; kc++)
        Af[kc] = *(const bf16x8*)(hb + ((rowbase + r) << 7) + kc * 32 + q * 8);

#pragma unroll
    for (int nt = 0; nt < 8; nt++) {
        f32x4 acc = {0.f, 0.f, 0.f, 0.f};
#pragma unroll
        for (int kc = 0; kc < 4; kc++)
            acc = __builtin_amdgcn_mfma_f32_16x16x32_bf16(Af[kc], Bf[nt][kc], acc, 0, 0, 0);
#pragma unroll
        for (int i = 0; i < 4; i++)
            hwb[(rowbase + q * 4 + i) * 128 + nt * 16 + r] = f2bf(acc[i]);
    }
}

// ---- Aggregation: out[v] = relu( b + dinv[v]^2*hw[v] + sum norm_e*hw[src_e] )
// one wave per node, 2 features per lane (coalesced 256B row reads)
__global__ __launch_bounds__(256) void k_agg(const u16* __restrict__ hwb,
                                             const int* __restrict__ row_ptr,
                                             const int* __restrict__ csr_src,
                                             const float* __restrict__ csr_norm,
                                             const float* __restrict__ dinv,
                                             const float* __restrict__ bias,
                                             u16* __restrict__ bf_out,
                                             float* __restrict__ f_out,
                                             int write_f32) {
    int lane = threadIdx.x & 63;
    int v = blockIdx.x * 4 + (threadIdx.x >> 6);  // grid 12500 -> exact
    int f = lane << 1;
    float dv = dinv[v];
    u32 u = *(const u32*)(hwb + (size_t)v * DIM + f);
    float a0 = dv * dv * bf2f((u16)u);
    float a1 = dv * dv * bf2f((u16)(u >> 16));
    int e = row_ptr[v], end = row_ptr[v + 1];
    for (; e + 2 <= end; e += 2) {
        int s0 = csr_src[e], s1 = csr_src[e + 1];
        float n0 = csr_norm[e], n1 = csr_norm[e + 1];
        u32 u0 = *(const u32*)(hwb + (size_t)s0 * DIM + f);
        u32 u1 = *(const u32*)(hwb + (size_t)s1 * DIM + f);
        a0 += n0 * bf2f((u16)u0) + n1 * bf2f((u16)u1);
        a1 += n0 * bf2f((u16)(u0 >> 16)) + n1 * bf2f((u16)(u1 >> 16));
    }
    if (e < end) {
        int s0 = csr_src[e];
        float n0 = csr_norm[e];
        u32 u0 = *(const u32*)(hwb + (size_t)s0 * DIM + f);
        a0 += n0 * bf2f((u16)u0);
        a1 += n0 * bf2f((u16)(u0 >> 16));
    }
    a0 = fmaxf(a0 + bias[f], 0.f);
    a1 = fmaxf(a1 + bias[f + 1], 0.f);
    if (write_f32) {
        float2 o;
        o.x = a0;
        o.y = a1;
        *(float2*)(f_out + (size_t)v * DIM + f) = o;
    } else {
        u32 o = (u32)f2bf(a0) | ((u32)f2bf(a1) << 16);
        *(u32*)(bf_out + (size_t)v * DIM + f) = o;
    }
}

// ---- launch ----------------------------------------------------------------

extern "C" void kernel_launch(void* const* d_in, const int* in_sizes, int n_in,
                              void* d_out, int out_size, void* d_ws, size_t ws_size,
                              hipStream_t stream) {
    const float* x = (const float*)d_in[0];
    const int* ei = (const int*)d_in[1];
    const float* W0 = (const float*)d_in[2];
    const float* b0 = (const float*)d_in[3];
    const float* W1 = (const float*)d_in[4];
    const float* b1 = (const float*)d_in[5];
    const float* W2 = (const float*)d_in[6];
    const float* b2 = (const float*)d_in[7];

    char* ws = (char*)d_ws;
    size_t off = 0;
    auto alloc = [&](size_t bytes) -> void* {
        void* p = ws + off;
        off += (bytes + 511) & ~(size_t)511;
        return p;
    };
    int* deg = (int*)alloc(NN * 4);
    float* dinv = (float*)alloc(NN * 4);
    int* row_ptr = (int*)alloc((NN + 1) * 4);
    int* cursor = (int*)alloc(NN * 4);
    int* bsum = (int*)alloc(256 * 4);
    int* flag = (int*)alloc(512);
    int* csr_src = (int*)alloc(NE * 4);
    float* csr_norm = (float*)alloc(NE * 4);
    u16* Wt = (u16*)alloc(3 * 128 * 128 * 2);
    u16* xb = (u16*)alloc((size_t)NN * DIM * 2);
    u16* hwb = (u16*)alloc((size_t)NN * DIM * 2);
    u16* hb = (u16*)alloc((size_t)NN * DIM * 2);

    k_init<<<NB_N, 256, 0, stream>>>(ei, deg, flag);
    k_count<<<NB_E, 256, 0, stream>>>(ei, flag, deg);
    k_dinv<<<NB_N, 256, 0, stream>>>(deg, dinv, cursor);
    k_scanA<<<NB_N, 256, 0, stream>>>(deg, row_ptr, bsum);
    k_scanB<<<1, 256, 0, stream>>>(bsum);
    k_scanC<<<NB_N, 256, 0, stream>>>(row_ptr, bsum);
    k_fill<<<NB_E, 256, 0, stream>>>(ei, flag, row_ptr, cursor, dinv, csr_src, csr_norm);
    k_wcast<<<192, 256, 0, stream>>>(W0, W1, W2, Wt);
    k_xcast<<<6250, 256, 0, stream>>>(x, xb);

    // layer 1: xb -> hwb -> hb
    k_gemm<<<(TILES + 3) / 4, 256, 0, stream>>>(xb, Wt, hwb);
    k_agg<<<NN / 4, 256, 0, stream>>>(hwb, row_ptr, csr_src, csr_norm, dinv, b0, hb, nullptr, 0);
    // layer 2: hb -> hwb -> xb (reuse)
    k_gemm<<<(TILES + 3) / 4, 256, 0, stream>>>(hb, Wt + 16384, hwb);
    k_agg<<<NN / 4, 256, 0, stream>>>(hwb, row_ptr, csr_src, csr_norm, dinv, b1, xb, nullptr, 0);
    // layer 3: xb -> hwb -> d_out (f32)
    k_gemm<<<(TILES + 3) / 4, 256, 0, stream>>>(xb, Wt + 32768, hwb);
    k_agg<<<NN / 4, 256, 0, stream>>>(hwb, row_ptr, csr_src, csr_norm, dinv, b2, nullptr,
                                      (float*)d_out, 1);
}

// Round 2
// 295.826 us; speedup vs baseline: 1.2055x; 1.2055x over previous
//
#include <hip/hip_runtime.h>

#define NN 50000
#define NE 600000
#define DIM 128
#define NB_N 196   // ceil(50000/256)
#define NB_E 2344  // ceil(600000/256)
#define TILES 3125 // 50000/16
#define ROWW 136   // LDS row pitch in u16 (128 + 8 pad -> breaks b128 bank conflicts)

typedef unsigned short u16;
typedef unsigned int u32;
typedef __attribute__((ext_vector_type(8))) short bf16x8;
typedef __attribute__((ext_vector_type(4))) float f32x4;

__device__ __forceinline__ u16 f2bf(float f) {
    u32 u = __builtin_bit_cast(u32, f);
    u32 r = (u + 0x7FFFu + ((u >> 16) & 1u)) >> 16;
    return (u16)r;
}
__device__ __forceinline__ float bf2f(u16 h) {
    u32 u = ((u32)h) << 16;
    return __builtin_bit_cast(float, u);
}

// ---- CSR build -------------------------------------------------------------
// deg/cursor zeroed by hipMemsetAsync; deg counts real edges only, dinv uses +1.

__global__ __launch_bounds__(256) void k_count(const int* __restrict__ ei,
                                               int* __restrict__ deg) {
    __shared__ int s64;
    if (threadIdx.x == 0) {
        int o = 0;
#pragma unroll
        for (int j = 0; j < 16; j++) o |= ei[2 * j + 1];  // int64 => high words all 0
        s64 = (o == 0);
    }
    __syncthreads();
    int e = blockIdx.x * 256 + threadIdx.x;
    if (e >= NE) return;
    int d = s64 ? ei[2 * (NE + e)] : ei[NE + e];
    atomicAdd(&deg[d], 1);
}

// exclusive scan of deg -> row_ptr (two-level)
__global__ __launch_bounds__(256) void k_scanA(const int* __restrict__ deg,
                                               int* __restrict__ row_ptr,
                                               int* __restrict__ bsum) {
    __shared__ int buf[256];
    int t = threadIdx.x, i = blockIdx.x * 256 + t;
    int v = (i < NN) ? deg[i] : 0;
    buf[t] = v;
    __syncthreads();
    for (int off = 1; off < 256; off <<= 1) {
        int x = (t >= off) ? buf[t - off] : 0;
        __syncthreads();
        buf[t] += x;
        __syncthreads();
    }
    if (i < NN) row_ptr[i] = buf[t] - v;
    if (t == 255) bsum[blockIdx.x] = buf[255];
}

__global__ __launch_bounds__(256) void k_scanB(int* __restrict__ bsum) {
    __shared__ int buf[256];
    int t = threadIdx.x;
    int v = (t < NB_N) ? bsum[t] : 0;
    buf[t] = v;
    __syncthreads();
    for (int off = 1; off < 256; off <<= 1) {
        int x = (t >= off) ? buf[t - off] : 0;
        __syncthreads();
        buf[t] += x;
        __syncthreads();
    }
    bsum[t] = buf[t] - v;
}

__global__ __launch_bounds__(256) void k_scanC(const int* __restrict__ deg,
                                               int* __restrict__ row_ptr,
                                               const int* __restrict__ bsum,
                                               float* __restrict__ dinv) {
    int i = blockIdx.x * 256 + threadIdx.x;
    if (i < NN) {
        row_ptr[i] += bsum[i >> 8];
        dinv[i] = rsqrtf((float)(deg[i] + 1));  // +1 self loop
    }
    if (i == 0) row_ptr[NN] = NE;
}

__global__ __launch_bounds__(256) void k_fill(const int* __restrict__ ei,
                                              const int* __restrict__ row_ptr,
                                              int* __restrict__ cursor,
                                              const float* __restrict__ dinv,
                                              int* __restrict__ csr_src,
                                              float* __restrict__ csr_norm) {
    __shared__ int s64;
    if (threadIdx.x == 0) {
        int o = 0;
#pragma unroll
        for (int j = 0; j < 16; j++) o |= ei[2 * j + 1];
        s64 = (o == 0);
    }
    __syncthreads();
    int e = blockIdx.x * 256 + threadIdx.x;
    if (e >= NE) return;
    int is64 = s64;
    int s = is64 ? ei[2 * e] : ei[e];
    int d = is64 ? ei[2 * (NE + e)] : ei[NE + e];
    int pos = row_ptr[d] + atomicAdd(&cursor[d], 1);
    csr_src[pos] = s;
    csr_norm[pos] = dinv[s] * dinv[d];
}

// ---- weight cast: Wt[layer][n][k] = bf16(W[layer][k][n]) -------------------
__global__ __launch_bounds__(256) void k_wcast(const float* __restrict__ W0,
                                               const float* __restrict__ W1,
                                               const float* __restrict__ W2,
                                               u16* __restrict__ Wt) {
    int idx = blockIdx.x * 256 + threadIdx.x;  // < 3*16384
    int l = idx >> 14, rem = idx & 16383;
    int n = rem >> 7, k = rem & 127;
    const float* W = (l == 0) ? W0 : ((l == 1) ? W1 : W2);
    Wt[idx] = f2bf(W[k * 128 + n]);
}

// ---- layer-1 GEMM: hw[N,128] = bf16(x f32) @ W0 ----------------------------
__global__ __launch_bounds__(256) void k_gemm_f32(const float* __restrict__ x,
                                                  const u16* __restrict__ Wt,
                                                  u16* __restrict__ hwb) {
    int lane = threadIdx.x & 63;
    int tile = blockIdx.x * 4 + (threadIdx.x >> 6);
    if (tile >= TILES) return;
    int r = lane & 15, q = lane >> 4;

    bf16x8 Bf[8][4];
#pragma unroll
    for (int nt = 0; nt < 8; nt++)
#pragma unroll
        for (int kc = 0; kc < 4; kc++)
            Bf[nt][kc] = *(const bf16x8*)(Wt + ((nt * 16 + r) << 7) + kc * 32 + q * 8);

    long rowbase = (long)tile * 16;
    bf16x8 Af[4];
#pragma unroll
    for (int kc = 0; kc < 4; kc++) {
        const float4* p = (const float4*)(x + (rowbase + r) * 128 + kc * 32 + q * 8);
        float4 t0 = p[0], t1 = p[1];
        bf16x8 a;
        a[0] = (short)f2bf(t0.x); a[1] = (short)f2bf(t0.y);
        a[2] = (short)f2bf(t0.z); a[3] = (short)f2bf(t0.w);
        a[4] = (short)f2bf(t1.x); a[5] = (short)f2bf(t1.y);
        a[6] = (short)f2bf(t1.z); a[7] = (short)f2bf(t1.w);
        Af[kc] = a;
    }

#pragma unroll
    for (int nt = 0; nt < 8; nt++) {
        f32x4 acc = {0.f, 0.f, 0.f, 0.f};
#pragma unroll
        for (int kc = 0; kc < 4; kc++)
            acc = __builtin_amdgcn_mfma_f32_16x16x32_bf16(Af[kc], Bf[nt][kc], acc, 0, 0, 0);
#pragma unroll
        for (int i = 0; i < 4; i++)
            hwb[(rowbase + q * 4 + i) * 128 + nt * 16 + r] = f2bf(acc[i]);
    }
}

// ---- aggregation core: a = dinv[v]^2*hw[v] + sum norm_e*hw[src_e], 2 f/lane
// 4-unrolled: 4 independent gathers in flight per wave (latency hiding)
__device__ __forceinline__ void agg_node(const u16* __restrict__ hw,
                                         const int* __restrict__ rp,
                                         const int* __restrict__ cs,
                                         const float* __restrict__ cn,
                                         float dv, int v, int f,
                                         float& a0, float& a1) {
    u32 u = *(const u32*)(hw + (size_t)v * DIM + f);
    a0 = dv * dv * bf2f((u16)u);
    a1 = dv * dv * bf2f((u16)(u >> 16));
    int e = rp[v], end = rp[v + 1];
    for (; e + 4 <= end; e += 4) {
        int s0 = cs[e], s1 = cs[e + 1], s2 = cs[e + 2], s3 = cs[e + 3];
        float n0 = cn[e], n1 = cn[e + 1], n2 = cn[e + 2], n3 = cn[e + 3];
        u32 u0 = *(const u32*)(hw + (size_t)s0 * DIM + f);
        u32 u1 = *(const u32*)(hw + (size_t)s1 * DIM + f);
        u32 u2 = *(const u32*)(hw + (size_t)s2 * DIM + f);
        u32 u3 = *(const u32*)(hw + (size_t)s3 * DIM + f);
        a0 += n0 * bf2f((u16)u0) + n1 * bf2f((u16)u1) +
              n2 * bf2f((u16)u2) + n3 * bf2f((u16)u3);
        a1 += n0 * bf2f((u16)(u0 >> 16)) + n1 * bf2f((u16)(u1 >> 16)) +
              n2 * bf2f((u16)(u2 >> 16)) + n3 * bf2f((u16)(u3 >> 16));
    }
    for (; e < end; e++) {
        int s0 = cs[e];
        float n0 = cn[e];
        u32 u0 = *(const u32*)(hw + (size_t)s0 * DIM + f);
        a0 += n0 * bf2f((u16)u0);
        a1 += n0 * bf2f((u16)(u0 >> 16));
    }
}

// ---- fused: h = relu(agg(hw_in)+b) -> LDS tile -> hw_out = h @ W -----------
// block = 16 nodes (1 MFMA m-tile), 4 waves; wave w aggregates nodes w*4..w*4+3
__global__ __launch_bounds__(256) void k_agg_gemm(const u16* __restrict__ hw_in,
                                                  const int* __restrict__ rp,
                                                  const int* __restrict__ cs,
                                                  const float* __restrict__ cn,
                                                  const float* __restrict__ dinv,
                                                  const float* __restrict__ bias,
                                                  const u16* __restrict__ Wt,
                                                  u16* __restrict__ hw_out) {
    __shared__ u16 sm[16 * ROWW];
    int lane = threadIdx.x & 63;
    int w = threadIdx.x >> 6;
    int base = blockIdx.x * 16;
    int f = lane << 1;
    float bv0 = bias[f], bv1 = bias[f + 1];
#pragma unroll
    for (int ni = 0; ni < 4; ni++) {
        int v = base + w * 4 + ni;
        float a0, a1;
        agg_node(hw_in, rp, cs, cn, dinv[v], v, f, a0, a1);
        a0 = fmaxf(a0 + bv0, 0.f);
        a1 = fmaxf(a1 + bv1, 0.f);
        u32 o = (u32)f2bf(a0) | ((u32)f2bf(a1) << 16);
        ((u32*)sm)[(w * 4 + ni) * (ROWW / 2) + lane] = o;
    }
    __syncthreads();
    // GEMM: 16x128 tile (LDS) @ 128x128 W; wave w does n-tiles {2w, 2w+1}
    int r = lane & 15, q = lane >> 4;
    bf16x8 Af[4];
#pragma unroll
    for (int kc = 0; kc < 4; kc++)
        Af[kc] = *(const bf16x8*)(sm + r * ROWW + kc * 32 + q * 8);
#pragma unroll
    for (int t = 0; t < 2; t++) {
        int nt = w * 2 + t;
        f32x4 acc = {0.f, 0.f, 0.f, 0.f};
#pragma unroll
        for (int kc = 0; kc < 4; kc++) {
            bf16x8 Bf = *(const bf16x8*)(Wt + ((nt * 16 + r) << 7) + kc * 32 + q * 8);
            acc = __builtin_amdgcn_mfma_f32_16x16x32_bf16(Af[kc], Bf, acc, 0, 0, 0);
        }
#pragma unroll
        for (int i = 0; i < 4; i++)
            hw_out[(size_t)(base + q * 4 + i) * DIM + nt * 16 + r] = f2bf(acc[i]);
    }
}

// ---- final layer: relu(agg+b) -> f32 out -----------------------------------
__global__ __launch_bounds__(256) void k_agg_out(const u16* __restrict__ hw_in,
                                                 const int* __restrict__ rp,
                                                 const int* __restrict__ cs,
                                                 const float* __restrict__ cn,
                                                 const float* __restrict__ dinv,
                                                 const float* __restrict__ bias,
                                                 float* __restrict__ out) {
    int lane = threadIdx.x & 63;
    int v = blockIdx.x * 4 + (threadIdx.x >> 6);  // grid 12500 exact
    int f = lane << 1;
    float a0, a1;
    agg_node(hw_in, rp, cs, cn, dinv[v], v, f, a0, a1);
    float2 o;
    o.x = fmaxf(a0 + bias[f], 0.f);
    o.y = fmaxf(a1 + bias[f + 1], 0.f);
    *(float2*)(out + (size_t)v * DIM + f) = o;
}

// ---- launch ----------------------------------------------------------------

extern "C" void kernel_launch(void* const* d_in, const int* in_sizes, int n_in,
                              void* d_out, int out_size, void* d_ws, size_t ws_size,
                              hipStream_t stream) {
    const float* x = (const float*)d_in[0];
    const int* ei = (const int*)d_in[1];
    const float* W0 = (const float*)d_in[2];
    const float* b0 = (const float*)d_in[3];
    const float* W1 = (const float*)d_in[4];
    const float* b1 = (const float*)d_in[5];
    const float* W2 = (const float*)d_in[6];
    const float* b2 = (const float*)d_in[7];

    char* ws = (char*)d_ws;
    size_t off = 0;
    auto alloc = [&](size_t bytes) -> void* {
        void* p = ws + off;
        off += (bytes + 511) & ~(size_t)511;
        return p;
    };
    int* deg = (int*)alloc(2 * NN * 4);  // deg + cursor contiguous (one memset)
    int* cursor = deg + NN;
    float* dinv = (float*)alloc(NN * 4);
    int* row_ptr = (int*)alloc((NN + 1) * 4);
    int* bsum = (int*)alloc(256 * 4);
    int* csr_src = (int*)alloc(NE * 4);
    float* csr_norm = (float*)alloc(NE * 4);
    u16* Wt = (u16*)alloc(3 * 128 * 128 * 2);
    u16* hwA = (u16*)alloc((size_t)NN * DIM * 2);
    u16* hwB = (u16*)alloc((size_t)NN * DIM * 2);

    hipMemsetAsync(deg, 0, 2 * NN * 4, stream);
    k_count<<<NB_E, 256, 0, stream>>>(ei, deg);
    k_scanA<<<NB_N, 256, 0, stream>>>(deg, row_ptr, bsum);
    k_scanB<<<1, 256, 0, stream>>>(bsum);
    k_scanC<<<NB_N, 256, 0, stream>>>(deg, row_ptr, bsum, dinv);
    k_fill<<<NB_E, 256, 0, stream>>>(ei, row_ptr, cursor, dinv, csr_src, csr_norm);
    k_wcast<<<192, 256, 0, stream>>>(W0, W1, W2, Wt);

    k_gemm_f32<<<(TILES + 3) / 4, 256, 0, stream>>>(x, Wt, hwA);                 // hw1
    k_agg_gemm<<<TILES, 256, 0, stream>>>(hwA, row_ptr, csr_src, csr_norm,
                                          dinv, b0, Wt + 16384, hwB);            // hw2
    k_agg_gemm<<<TILES, 256, 0, stream>>>(hwB, row_ptr, csr_src, csr_norm,
                                          dinv, b1, Wt + 32768, hwA);            // hw3
    k_agg_out<<<NN / 4, 256, 0, stream>>>(hwA, row_ptr, csr_src, csr_norm,
                                          dinv, b2, (float*)d_out);
}

// Round 3
// 281.402 us; speedup vs baseline: 1.2672x; 1.0513x over previous
//
#include <hip/hip_runtime.h>

#define NN 50000
#define NE 600000
#define DIM 128
#define NB_N 196   // ceil(50000/256)
#define NB_E 2344  // ceil(600000/256)
#define TILES 3125 // 50000/16
#define ROWW 136   // LDS row pitch in u16 (128 + 8 pad)
#define NEPAD (NE + 3 * NN + 4096)  // padded CSR capacity

typedef unsigned short u16;
typedef unsigned int u32;
typedef __attribute__((ext_vector_type(8))) short bf16x8;
typedef __attribute__((ext_vector_type(4))) float f32x4;

__device__ __forceinline__ u16 f2bf(float f) {
    u32 u = __builtin_bit_cast(u32, f);
    u32 r = (u + 0x7FFFu + ((u >> 16) & 1u)) >> 16;
    return (u16)r;
}
__device__ __forceinline__ float bflo(u32 w) { return __builtin_bit_cast(float, w << 16); }
__device__ __forceinline__ float bfhi(u32 w) { return __builtin_bit_cast(float, w & 0xffff0000u); }

// ---- CSR build (rows padded to multiple of 4; pad entries src=0,norm=0) ----

__global__ __launch_bounds__(256) void k_count(const int* __restrict__ ei,
                                               int* __restrict__ deg) {
    __shared__ int s64;
    if (threadIdx.x == 0) {
        int o = 0;
#pragma unroll
        for (int j = 0; j < 16; j++) o |= ei[2 * j + 1];  // int64 => high words 0
        s64 = (o == 0);
    }
    __syncthreads();
    int e = blockIdx.x * 256 + threadIdx.x;
    if (e >= NE) return;
    int d = s64 ? ei[2 * (NE + e)] : ei[NE + e];
    atomicAdd(&deg[d], 1);
}

// exclusive scan of padded degree -> rp4
__global__ __launch_bounds__(256) void k_scanA(const int* __restrict__ deg,
                                               int* __restrict__ rp4,
                                               int* __restrict__ bsum) {
    __shared__ int buf[256];
    int t = threadIdx.x, i = blockIdx.x * 256 + t;
    int v = (i < NN) ? ((deg[i] + 3) & ~3) : 0;
    buf[t] = v;
    __syncthreads();
    for (int off = 1; off < 256; off <<= 1) {
        int x = (t >= off) ? buf[t - off] : 0;
        __syncthreads();
        buf[t] += x;
        __syncthreads();
    }
    if (i < NN) rp4[i] = buf[t] - v;
    if (t == 255) bsum[blockIdx.x] = buf[255];
}

__global__ __launch_bounds__(256) void k_scanB(int* __restrict__ bsum) {
    __shared__ int buf[256];
    int t = threadIdx.x;
    int v = (t < NB_N) ? bsum[t] : 0;
    buf[t] = v;
    __syncthreads();
    for (int off = 1; off < 256; off <<= 1) {
        int x = (t >= off) ? buf[t - off] : 0;
        __syncthreads();
        buf[t] += x;
        __syncthreads();
    }
    bsum[t] = buf[t] - v;  // t >= NB_N: total padded count
}

__global__ __launch_bounds__(256) void k_scanC(const int* __restrict__ deg,
                                               int* __restrict__ rp4,
                                               const int* __restrict__ bsum,
                                               float* __restrict__ dinv) {
    int i = blockIdx.x * 256 + threadIdx.x;
    if (i < NN) {
        rp4[i] += bsum[i >> 8];
        dinv[i] = rsqrtf((float)(deg[i] + 1));  // +1 self loop
    }
    if (i == 0) rp4[NN] = bsum[255];  // total padded entries
}

__global__ __launch_bounds__(256) void k_fill(const int* __restrict__ ei,
                                              const int* __restrict__ rp4,
                                              int* __restrict__ cursor,
                                              const float* __restrict__ dinv,
                                              int* __restrict__ csr_src,
                                              float* __restrict__ csr_norm) {
    __shared__ int s64;
    if (threadIdx.x == 0) {
        int o = 0;
#pragma unroll
        for (int j = 0; j < 16; j++) o |= ei[2 * j + 1];
        s64 = (o == 0);
    }
    __syncthreads();
    int e = blockIdx.x * 256 + threadIdx.x;
    if (e >= NE) return;
    int is64 = s64;
    int s = is64 ? ei[2 * e] : ei[e];
    int d = is64 ? ei[2 * (NE + e)] : ei[NE + e];
    int pos = rp4[d] + atomicAdd(&cursor[d], 1);
    csr_src[pos] = s;
    csr_norm[pos] = dinv[s] * dinv[d];
}

// ---- weight cast: Wt[layer][n][k] = bf16(W[layer][k][n]) -------------------
__global__ __launch_bounds__(256) void k_wcast(const float* __restrict__ W0,
                                               const float* __restrict__ W1,
                                               const float* __restrict__ W2,
                                               u16* __restrict__ Wt) {
    int idx = blockIdx.x * 256 + threadIdx.x;  // < 3*16384
    int l = idx >> 14, rem = idx & 16383;
    int n = rem >> 7, k = rem & 127;
    const float* W = (l == 0) ? W0 : ((l == 1) ? W1 : W2);
    Wt[idx] = f2bf(W[k * 128 + n]);
}

// ---- layer-1 GEMM: hw[N,128] = bf16(x f32) @ W0 ----------------------------
__global__ __launch_bounds__(256) void k_gemm_f32(const float* __restrict__ x,
                                                  const u16* __restrict__ Wt,
                                                  u16* __restrict__ hwb) {
    int lane = threadIdx.x & 63;
    int tile = blockIdx.x * 4 + (threadIdx.x >> 6);
    if (tile >= TILES) return;
    int r = lane & 15, q = lane >> 4;

    bf16x8 Bf[8][4];
#pragma unroll
    for (int nt = 0; nt < 8; nt++)
#pragma unroll
        for (int kc = 0; kc < 4; kc++)
            Bf[nt][kc] = *(const bf16x8*)(Wt + ((nt * 16 + r) << 7) + kc * 32 + q * 8);

    long rowbase = (long)tile * 16;
    bf16x8 Af[4];
#pragma unroll
    for (int kc = 0; kc < 4; kc++) {
        const float4* p = (const float4*)(x + (rowbase + r) * 128 + kc * 32 + q * 8);
        float4 t0 = p[0], t1 = p[1];
        bf16x8 a;
        a[0] = (short)f2bf(t0.x); a[1] = (short)f2bf(t0.y);
        a[2] = (short)f2bf(t0.z); a[3] = (short)f2bf(t0.w);
        a[4] = (short)f2bf(t1.x); a[5] = (short)f2bf(t1.y);
        a[6] = (short)f2bf(t1.z); a[7] = (short)f2bf(t1.w);
        Af[kc] = a;
    }

#pragma unroll
    for (int nt = 0; nt < 8; nt++) {
        f32x4 acc = {0.f, 0.f, 0.f, 0.f};
#pragma unroll
        for (int kc = 0; kc < 4; kc++)
            acc = __builtin_amdgcn_mfma_f32_16x16x32_bf16(Af[kc], Bf[nt][kc], acc, 0, 0, 0);
#pragma unroll
        for (int i = 0; i < 4; i++)
            hwb[(rowbase + q * 4 + i) * 128 + nt * 16 + r] = f2bf(acc[i]);
    }
}

// ---- aggregation core: wave = 1 node; group g=lane>>4 handles edge e+g,
// lane r=lane&15 holds features 8r..8r+7 (one dwordx4 per edge-group).
__device__ __forceinline__ void fma8(float* acc, uint4 u, float n) {
    acc[0] += n * bflo(u.x); acc[1] += n * bfhi(u.x);
    acc[2] += n * bflo(u.y); acc[3] += n * bfhi(u.y);
    acc[4] += n * bflo(u.z); acc[5] += n * bfhi(u.z);
    acc[6] += n * bflo(u.w); acc[7] += n * bfhi(u.w);
}

__device__ __forceinline__ void agg_node16(const u16* __restrict__ hw,
                                           const int* __restrict__ rp4,
                                           const int* __restrict__ cs,
                                           const float* __restrict__ cn,
                                           const float* __restrict__ bias,
                                           float dv, int v, int g, int r,
                                           float* acc) {
    uint4 sv = *(const uint4*)(hw + (size_t)v * DIM + r * 8);
    float sc = (g == 0) ? dv * dv : 0.0f;  // self term counted once
    acc[0] = sc * bflo(sv.x); acc[1] = sc * bfhi(sv.x);
    acc[2] = sc * bflo(sv.y); acc[3] = sc * bfhi(sv.y);
    acc[4] = sc * bflo(sv.z); acc[5] = sc * bfhi(sv.z);
    acc[6] = sc * bflo(sv.w); acc[7] = sc * bfhi(sv.w);
    int e = rp4[v], end = rp4[v + 1];
    for (; e + 8 <= end; e += 8) {
        int s0 = cs[e + g], s1 = cs[e + 4 + g];
        float n0 = cn[e + g], n1 = cn[e + 4 + g];
        uint4 u0 = *(const uint4*)(hw + (size_t)s0 * DIM + r * 8);
        uint4 u1 = *(const uint4*)(hw + (size_t)s1 * DIM + r * 8);
        fma8(acc, u0, n0);
        fma8(acc, u1, n1);
    }
    if (e < end) {  // padded to 4 -> exactly one 4-edge tail
        int s0 = cs[e + g];
        float n0 = cn[e + g];
        uint4 u0 = *(const uint4*)(hw + (size_t)s0 * DIM + r * 8);
        fma8(acc, u0, n0);
    }
#pragma unroll
    for (int j = 0; j < 8; j++) {  // combine 4 groups
        acc[j] += __shfl_xor(acc[j], 16, 64);
        acc[j] += __shfl_xor(acc[j], 32, 64);
    }
    float4 b0 = ((const float4*)bias)[2 * r];
    float4 b1 = ((const float4*)bias)[2 * r + 1];
    acc[0] = fmaxf(acc[0] + b0.x, 0.f); acc[1] = fmaxf(acc[1] + b0.y, 0.f);
    acc[2] = fmaxf(acc[2] + b0.z, 0.f); acc[3] = fmaxf(acc[3] + b0.w, 0.f);
    acc[4] = fmaxf(acc[4] + b1.x, 0.f); acc[5] = fmaxf(acc[5] + b1.y, 0.f);
    acc[6] = fmaxf(acc[6] + b1.z, 0.f); acc[7] = fmaxf(acc[7] + b1.w, 0.f);
}

// ---- fused: h = relu(agg(hw_in)+b) -> LDS tile -> hw_out = h @ W -----------
// block = 16 nodes, 4 waves; wave w aggregates nodes w*4..w*4+3 (1 node/pass)
__global__ __launch_bounds__(256) void k_agg_gemm(const u16* __restrict__ hw_in,
                                                  const int* __restrict__ rp4,
                                                  const int* __restrict__ cs,
                                                  const float* __restrict__ cn,
                                                  const float* __restrict__ dinv,
                                                  const float* __restrict__ bias,
                                                  const u16* __restrict__ Wt,
                                                  u16* __restrict__ hw_out) {
    __shared__ u16 sm[16 * ROWW];
    int lane = threadIdx.x & 63;
    int w = threadIdx.x >> 6;
    int g = lane >> 4, r = lane & 15;
    int base = blockIdx.x * 16;
#pragma unroll
    for (int ni = 0; ni < 4; ni++) {
        int row = w * 4 + ni, v = base + row;
        float acc[8];
        agg_node16(hw_in, rp4, cs, cn, bias, dinv[v], v, g, r, acc);
        if (g == 0) {
            uint4 p;
            p.x = (u32)f2bf(acc[0]) | ((u32)f2bf(acc[1]) << 16);
            p.y = (u32)f2bf(acc[2]) | ((u32)f2bf(acc[3]) << 16);
            p.z = (u32)f2bf(acc[4]) | ((u32)f2bf(acc[5]) << 16);
            p.w = (u32)f2bf(acc[6]) | ((u32)f2bf(acc[7]) << 16);
            *(uint4*)(sm + row * ROWW + r * 8) = p;
        }
    }
    __syncthreads();
    // GEMM: 16x128 LDS tile @ 128x128 W; wave w does n-tiles {2w, 2w+1}
    int q = lane >> 4;
    bf16x8 Af[4];
#pragma unroll
    for (int kc = 0; kc < 4; kc++)
        Af[kc] = *(const bf16x8*)(sm + r * ROWW + kc * 32 + q * 8);
#pragma unroll
    for (int t = 0; t < 2; t++) {
        int nt = w * 2 + t;
        f32x4 acc = {0.f, 0.f, 0.f, 0.f};
#pragma unroll
        for (int kc = 0; kc < 4; kc++) {
            bf16x8 Bf = *(const bf16x8*)(Wt + ((nt * 16 + r) << 7) + kc * 32 + q * 8);
            acc = __builtin_amdgcn_mfma_f32_16x16x32_bf16(Af[kc], Bf, acc, 0, 0, 0);
        }
#pragma unroll
        for (int i = 0; i < 4; i++)
            hw_out[(size_t)(base + q * 4 + i) * DIM + nt * 16 + r] = f2bf(acc[i]);
    }
}

// ---- final layer: relu(agg+b) -> f32 out, 1 node per wave ------------------
__global__ __launch_bounds__(256) void k_agg_out(const u16* __restrict__ hw_in,
                                                 const int* __restrict__ rp4,
                                                 const int* __restrict__ cs,
                                                 const float* __restrict__ cn,
                                                 const float* __restrict__ dinv,
                                                 const float* __restrict__ bias,
                                                 float* __restrict__ out) {
    int lane = threadIdx.x & 63;
    int w = threadIdx.x >> 6;
    int g = lane >> 4, r = lane & 15;
    int v = blockIdx.x * 4 + w;  // grid 12500 exact
    float acc[8];
    agg_node16(hw_in, rp4, cs, cn, bias, dinv[v], v, g, r, acc);
    if (g == 0) {
        float4 o0 = {acc[0], acc[1], acc[2], acc[3]};
        float4 o1 = {acc[4], acc[5], acc[6], acc[7]};
        float4* p = (float4*)(out + (size_t)v * DIM + r * 8);
        p[0] = o0;
        p[1] = o1;
    }
}

// ---- launch ----------------------------------------------------------------

extern "C" void kernel_launch(void* const* d_in, const int* in_sizes, int n_in,
                              void* d_out, int out_size, void* d_ws, size_t ws_size,
                              hipStream_t stream) {
    const float* x = (const float*)d_in[0];
    const int* ei = (const int*)d_in[1];
    const float* W0 = (const float*)d_in[2];
    const float* b0 = (const float*)d_in[3];
    const float* W1 = (const float*)d_in[4];
    const float* b1 = (const float*)d_in[5];
    const float* W2 = (const float*)d_in[6];
    const float* b2 = (const float*)d_in[7];

    char* ws = (char*)d_ws;
    size_t off = 0;
    auto alloc = [&](size_t bytes) -> void* {
        void* p = ws + off;
        off += (bytes + 511) & ~(size_t)511;
        return p;
    };
    // zero-region first: deg, cursor, padded CSR (norm pad entries must be 0)
    int* deg = (int*)alloc(NN * 4);
    int* cursor = (int*)alloc(NN * 4);
    int* csr_src = (int*)alloc((size_t)NEPAD * 4);
    float* csr_norm = (float*)alloc((size_t)NEPAD * 4);
    size_t zbytes = off;
    float* dinv = (float*)alloc(NN * 4);
    int* rp4 = (int*)alloc((NN + 1) * 4);
    int* bsum = (int*)alloc(256 * 4);
    u16* Wt = (u16*)alloc(3 * 128 * 128 * 2);
    u16* hwA = (u16*)alloc((size_t)NN * DIM * 2);
    u16* hwB = (u16*)alloc((size_t)NN * DIM * 2);

    hipMemsetAsync(ws, 0, zbytes, stream);
    k_count<<<NB_E, 256, 0, stream>>>(ei, deg);
    k_scanA<<<NB_N, 256, 0, stream>>>(deg, rp4, bsum);
    k_scanB<<<1, 256, 0, stream>>>(bsum);
    k_scanC<<<NB_N, 256, 0, stream>>>(deg, rp4, bsum, dinv);
    k_fill<<<NB_E, 256, 0, stream>>>(ei, rp4, cursor, dinv, csr_src, csr_norm);
    k_wcast<<<192, 256, 0, stream>>>(W0, W1, W2, Wt);

    k_gemm_f32<<<(TILES + 3) / 4, 256, 0, stream>>>(x, Wt, hwA);                 // hw1
    k_agg_gemm<<<TILES, 256, 0, stream>>>(hwA, rp4, csr_src, csr_norm,
                                          dinv, b0, Wt + 16384, hwB);            // hw2
    k_agg_gemm<<<TILES, 256, 0, stream>>>(hwB, rp4, csr_src, csr_norm,
                                          dinv, b1, Wt + 32768, hwA);            // hw3
    k_agg_out<<<NN / 4, 256, 0, stream>>>(hwA, rp4, csr_src, csr_norm,
                                          dinv, b2, (float*)d_out);
}

// Round 4
// 277.924 us; speedup vs baseline: 1.2831x; 1.0125x over previous
//
#include <hip/hip_runtime.h>

#define NN 50000
#define NE 600000
#define DIM 128
#define NB_N 196   // ceil(50000/256)
#define NB_E 2344  // ceil(600000/256)
#define TILES 3125 // 50000/16
#define ROWW 136   // LDS row pitch in u16 (128 + 8 pad)
#define NEPAD (NE + 8 * NN + 64)  // rows padded to multiple of 8, min 8

typedef unsigned short u16;
typedef unsigned int u32;
typedef __attribute__((ext_vector_type(8))) short bf16x8;
typedef __attribute__((ext_vector_type(4))) float f32x4;

__device__ __forceinline__ u16 f2bf(float f) {
    u32 u = __builtin_bit_cast(u32, f);
    u32 r = (u + 0x7FFFu + ((u >> 16) & 1u)) >> 16;
    return (u16)r;
}
__device__ __forceinline__ float bflo(u32 w) { return __builtin_bit_cast(float, w << 16); }
__device__ __forceinline__ float bfhi(u32 w) { return __builtin_bit_cast(float, w & 0xffff0000u); }
__device__ __forceinline__ float i2f(int b) { return __builtin_bit_cast(float, b); }

// ---- CSR build (rows padded to multiple of 8, min 8; pad recs = {0,0}) -----

__global__ __launch_bounds__(256) void k_count(const int* __restrict__ ei,
                                               int* __restrict__ deg) {
    __shared__ int s64;
    if (threadIdx.x == 0) {
        int o = 0;
#pragma unroll
        for (int j = 0; j < 16; j++) o |= ei[2 * j + 1];  // int64 => high words 0
        s64 = (o == 0);
    }
    __syncthreads();
    int e = blockIdx.x * 256 + threadIdx.x;
    if (e >= NE) return;
    int d = s64 ? ei[2 * (NE + e)] : ei[NE + e];
    atomicAdd(&deg[d], 1);
}

__global__ __launch_bounds__(256) void k_scanA(const int* __restrict__ deg,
                                               int* __restrict__ rp8,
                                               int* __restrict__ bsum) {
    __shared__ int buf[256];
    int t = threadIdx.x, i = blockIdx.x * 256 + t;
    int v = 0;
    if (i < NN) {
        v = (deg[i] + 7) & ~7;
        if (v == 0) v = 8;  // guarantee >=1 loop iteration per node
    }
    buf[t] = v;
    __syncthreads();
    for (int off = 1; off < 256; off <<= 1) {
        int x = (t >= off) ? buf[t - off] : 0;
        __syncthreads();
        buf[t] += x;
        __syncthreads();
    }
    if (i < NN) rp8[i] = buf[t] - v;
    if (t == 255) bsum[blockIdx.x] = buf[255];
}

__global__ __launch_bounds__(256) void k_scanB(int* __restrict__ bsum) {
    __shared__ int buf[256];
    int t = threadIdx.x;
    int v = (t < NB_N) ? bsum[t] : 0;
    buf[t] = v;
    __syncthreads();
    for (int off = 1; off < 256; off <<= 1) {
        int x = (t >= off) ? buf[t - off] : 0;
        __syncthreads();
        buf[t] += x;
        __syncthreads();
    }
    bsum[t] = buf[t] - v;  // t >= NB_N holds grand total
}

__global__ __launch_bounds__(256) void k_scanC(const int* __restrict__ deg,
                                               int* __restrict__ rp8,
                                               const int* __restrict__ bsum,
                                               float* __restrict__ dinv) {
    int i = blockIdx.x * 256 + threadIdx.x;
    if (i < NN) {
        rp8[i] += bsum[i >> 8];
        dinv[i] = rsqrtf((float)(deg[i] + 1));  // +1 self loop
    }
    if (i == 0) rp8[NN] = bsum[255];
}

// recs[pos] = {src, bits(norm)}
__global__ __launch_bounds__(256) void k_fill(const int* __restrict__ ei,
                                              const int* __restrict__ rp8,
                                              int* __restrict__ cursor,
                                              const float* __restrict__ dinv,
                                              int2* __restrict__ recs) {
    __shared__ int s64;
    if (threadIdx.x == 0) {
        int o = 0;
#pragma unroll
        for (int j = 0; j < 16; j++) o |= ei[2 * j + 1];
        s64 = (o == 0);
    }
    __syncthreads();
    int e = blockIdx.x * 256 + threadIdx.x;
    if (e >= NE) return;
    int is64 = s64;
    int s = is64 ? ei[2 * e] : ei[e];
    int d = is64 ? ei[2 * (NE + e)] : ei[NE + e];
    int pos = rp8[d] + atomicAdd(&cursor[d], 1);
    int2 rc;
    rc.x = s;
    rc.y = __builtin_bit_cast(int, dinv[s] * dinv[d]);
    recs[pos] = rc;
}

// ---- weight cast: Wt[layer][n][k] = bf16(W[layer][k][n]) -------------------
__global__ __launch_bounds__(256) void k_wcast(const float* __restrict__ W0,
                                               const float* __restrict__ W1,
                                               const float* __restrict__ W2,
                                               u16* __restrict__ Wt) {
    int idx = blockIdx.x * 256 + threadIdx.x;  // < 3*16384
    int l = idx >> 14, rem = idx & 16383;
    int n = rem >> 7, k = rem & 127;
    const float* W = (l == 0) ? W0 : ((l == 1) ? W1 : W2);
    Wt[idx] = f2bf(W[k * 128 + n]);
}

// ---- layer-1 GEMM: hw[N,128] = bf16(x f32) @ W0 ----------------------------
__global__ __launch_bounds__(256) void k_gemm_f32(const float* __restrict__ x,
                                                  const u16* __restrict__ Wt,
                                                  u16* __restrict__ hwb) {
    int lane = threadIdx.x & 63;
    int tile = blockIdx.x * 4 + (threadIdx.x >> 6);
    if (tile >= TILES) return;
    int r = lane & 15, q = lane >> 4;

    bf16x8 Bf[8][4];
#pragma unroll
    for (int nt = 0; nt < 8; nt++)
#pragma unroll
        for (int kc = 0; kc < 4; kc++)
            Bf[nt][kc] = *(const bf16x8*)(Wt + ((nt * 16 + r) << 7) + kc * 32 + q * 8);

    long rowbase = (long)tile * 16;
    bf16x8 Af[4];
#pragma unroll
    for (int kc = 0; kc < 4; kc++) {
        const float4* p = (const float4*)(x + (rowbase + r) * 128 + kc * 32 + q * 8);
        float4 t0 = p[0], t1 = p[1];
        bf16x8 a;
        a[0] = (short)f2bf(t0.x); a[1] = (short)f2bf(t0.y);
        a[2] = (short)f2bf(t0.z); a[3] = (short)f2bf(t0.w);
        a[4] = (short)f2bf(t1.x); a[5] = (short)f2bf(t1.y);
        a[6] = (short)f2bf(t1.z); a[7] = (short)f2bf(t1.w);
        Af[kc] = a;
    }

#pragma unroll
    for (int nt = 0; nt < 8; nt++) {
        f32x4 acc = {0.f, 0.f, 0.f, 0.f};
#pragma unroll
        for (int kc = 0; kc < 4; kc++)
            acc = __builtin_amdgcn_mfma_f32_16x16x32_bf16(Af[kc], Bf[nt][kc], acc, 0, 0, 0);
#pragma unroll
        for (int i = 0; i < 4; i++)
            hwb[(rowbase + q * 4 + i) * 128 + nt * 16 + r] = f2bf(acc[i]);
    }
}

// ---- aggregation core: wave = 2 nodes interleaved (2 indep chains),
// group g=lane>>4 handles edges {e+2g, e+2g+1}; lane r=lane&15 holds feats 8r..
// Explicit software pipeline: next iter's records loaded before current FMAs.
__device__ __forceinline__ void fma8(float* acc, uint4 u, float n) {
    acc[0] += n * bflo(u.x); acc[1] += n * bfhi(u.x);
    acc[2] += n * bflo(u.y); acc[3] += n * bfhi(u.y);
    acc[4] += n * bflo(u.z); acc[5] += n * bfhi(u.z);
    acc[6] += n * bflo(u.w); acc[7] += n * bfhi(u.w);
}

__device__ __forceinline__ void self_init(const u16* hw, float dv, int v, int g,
                                          int r, float* acc) {
    uint4 sv = *(const uint4*)(hw + (size_t)v * DIM + r * 8);
    float sc = (g == 0) ? dv * dv : 0.0f;
    acc[0] = sc * bflo(sv.x); acc[1] = sc * bfhi(sv.x);
    acc[2] = sc * bflo(sv.y); acc[3] = sc * bfhi(sv.y);
    acc[4] = sc * bflo(sv.z); acc[5] = sc * bfhi(sv.z);
    acc[6] = sc * bflo(sv.w); acc[7] = sc * bfhi(sv.w);
}

__device__ __forceinline__ void combine_bias_relu(const float* bias, int r,
                                                  float* acc) {
#pragma unroll
    for (int j = 0; j < 8; j++) {
        acc[j] += __shfl_xor(acc[j], 16, 64);
        acc[j] += __shfl_xor(acc[j], 32, 64);
    }
    float4 b0 = ((const float4*)bias)[2 * r];
    float4 b1 = ((const float4*)bias)[2 * r + 1];
    acc[0] = fmaxf(acc[0] + b0.x, 0.f); acc[1] = fmaxf(acc[1] + b0.y, 0.f);
    acc[2] = fmaxf(acc[2] + b0.z, 0.f); acc[3] = fmaxf(acc[3] + b0.w, 0.f);
    acc[4] = fmaxf(acc[4] + b1.x, 0.f); acc[5] = fmaxf(acc[5] + b1.y, 0.f);
    acc[6] = fmaxf(acc[6] + b1.z, 0.f); acc[7] = fmaxf(acc[7] + b1.w, 0.f);
}

__device__ __forceinline__ void agg_pair(const u16* __restrict__ hw,
                                         const int* __restrict__ rp8,
                                         const int2* __restrict__ recs,
                                         const float* __restrict__ dinv,
                                         int va, int vb, int g, int r,
                                         float* A, float* B) {
    self_init(hw, dinv[va], va, g, r, A);
    self_init(hw, dinv[vb], vb, g, r, B);
    int ea = rp8[va], enda = rp8[va + 1];
    int eb = rp8[vb], endb = rp8[vb + 1];
    // every row has >= 8 entries, so first loads are in-row
    int4 qa = *(const int4*)(recs + ea + 2 * g);
    int4 qb = *(const int4*)(recs + eb + 2 * g);
    while (ea < enda || eb < endb) {
        float na0 = (ea < enda) ? i2f(qa.y) : 0.f;
        float na1 = (ea < enda) ? i2f(qa.w) : 0.f;
        float nb0 = (eb < endb) ? i2f(qb.y) : 0.f;
        float nb1 = (eb < endb) ? i2f(qb.w) : 0.f;
        uint4 ua0 = *(const uint4*)(hw + (size_t)(u32)qa.x * DIM + r * 8);
        uint4 ua1 = *(const uint4*)(hw + (size_t)(u32)qa.z * DIM + r * 8);
        uint4 ub0 = *(const uint4*)(hw + (size_t)(u32)qb.x * DIM + r * 8);
        uint4 ub1 = *(const uint4*)(hw + (size_t)(u32)qb.z * DIM + r * 8);
        ea += 8; eb += 8;
        int pa = min(ea, enda - 8);  // clamped: re-reads last block, norm zeroed
        int pb = min(eb, endb - 8);
        int4 qa_n = *(const int4*)(recs + pa + 2 * g);
        int4 qb_n = *(const int4*)(recs + pb + 2 * g);
        fma8(A, ua0, na0); fma8(A, ua1, na1);
        fma8(B, ub0, nb0); fma8(B, ub1, nb1);
        qa = qa_n; qb = qb_n;
    }
}

// ---- fused: h = relu(agg(hw_in)+b) -> LDS tile -> hw_out = h @ W -----------
// block = 16 nodes, 4 waves; wave w handles node pairs (w*4+2p, w*4+2p+1)
__global__ __launch_bounds__(256) void k_agg_gemm(const u16* __restrict__ hw_in,
                                                  const int* __restrict__ rp8,
                                                  const int2* __restrict__ recs,
                                                  const float* __restrict__ dinv,
                                                  const float* __restrict__ bias,
                                                  const u16* __restrict__ Wt,
                                                  u16* __restrict__ hw_out) {
    __shared__ u16 sm[16 * ROWW];
    int lane = threadIdx.x & 63;
    int w = threadIdx.x >> 6;
    int g = lane >> 4, r = lane & 15;
    int base = blockIdx.x * 16;
#pragma unroll
    for (int p = 0; p < 2; p++) {
        int rowa = w * 4 + 2 * p;
        int va = base + rowa;
        float A[8], B[8];
        agg_pair(hw_in, rp8, recs, dinv, va, va + 1, g, r, A, B);
        combine_bias_relu(bias, r, A);
        combine_bias_relu(bias, r, B);
        if (g == 0) {
            uint4 pk;
            pk.x = (u32)f2bf(A[0]) | ((u32)f2bf(A[1]) << 16);
            pk.y = (u32)f2bf(A[2]) | ((u32)f2bf(A[3]) << 16);
            pk.z = (u32)f2bf(A[4]) | ((u32)f2bf(A[5]) << 16);
            pk.w = (u32)f2bf(A[6]) | ((u32)f2bf(A[7]) << 16);
            *(uint4*)(sm + rowa * ROWW + r * 8) = pk;
            pk.x = (u32)f2bf(B[0]) | ((u32)f2bf(B[1]) << 16);
            pk.y = (u32)f2bf(B[2]) | ((u32)f2bf(B[3]) << 16);
            pk.z = (u32)f2bf(B[4]) | ((u32)f2bf(B[5]) << 16);
            pk.w = (u32)f2bf(B[6]) | ((u32)f2bf(B[7]) << 16);
            *(uint4*)(sm + (rowa + 1) * ROWW + r * 8) = pk;
        }
    }
    __syncthreads();
    // GEMM: 16x128 LDS tile @ 128x128 W; wave w does n-tiles {2w, 2w+1}
    int q = lane >> 4;
    bf16x8 Af[4];
#pragma unroll
    for (int kc = 0; kc < 4; kc++)
        Af[kc] = *(const bf16x8*)(sm + r * ROWW + kc * 32 + q * 8);
#pragma unroll
    for (int t = 0; t < 2; t++) {
        int nt = w * 2 + t;
        f32x4 acc = {0.f, 0.f, 0.f, 0.f};
#pragma unroll
        for (int kc = 0; kc < 4; kc++) {
            bf16x8 Bf = *(const bf16x8*)(Wt + ((nt * 16 + r) << 7) + kc * 32 + q * 8);
            acc = __builtin_amdgcn_mfma_f32_16x16x32_bf16(Af[kc], Bf, acc, 0, 0, 0);
        }
#pragma unroll
        for (int i = 0; i < 4; i++)
            hw_out[(size_t)(base + q * 4 + i) * DIM + nt * 16 + r] = f2bf(acc[i]);
    }
}

// ---- final layer: relu(agg+b) -> f32 out, 2 nodes per wave -----------------
__global__ __launch_bounds__(256) void k_agg_out(const u16* __restrict__ hw_in,
                                                 const int* __restrict__ rp8,
                                                 const int2* __restrict__ recs,
                                                 const float* __restrict__ dinv,
                                                 const float* __restrict__ bias,
                                                 float* __restrict__ out) {
    int lane = threadIdx.x & 63;
    int w = threadIdx.x >> 6;
    int g = lane >> 4, r = lane & 15;
    int va = blockIdx.x * 8 + w * 2;  // grid 6250 exact
    float A[8], B[8];
    agg_pair(hw_in, rp8, recs, dinv, va, va + 1, g, r, A, B);
    combine_bias_relu(bias, r, A);
    combine_bias_relu(bias, r, B);
    if (g == 0) {
        float4* p = (float4*)(out + (size_t)va * DIM + r * 8);
        p[0] = make_float4(A[0], A[1], A[2], A[3]);
        p[1] = make_float4(A[4], A[5], A[6], A[7]);
        p = (float4*)(out + (size_t)(va + 1) * DIM + r * 8);
        p[0] = make_float4(B[0], B[1], B[2], B[3]);
        p[1] = make_float4(B[4], B[5], B[6], B[7]);
    }
}

// ---- launch ----------------------------------------------------------------

extern "C" void kernel_launch(void* const* d_in, const int* in_sizes, int n_in,
                              void* d_out, int out_size, void* d_ws, size_t ws_size,
                              hipStream_t stream) {
    const float* x = (const float*)d_in[0];
    const int* ei = (const int*)d_in[1];
    const float* W0 = (const float*)d_in[2];
    const float* b0 = (const float*)d_in[3];
    const float* W1 = (const float*)d_in[4];
    const float* b1 = (const float*)d_in[5];
    const float* W2 = (const float*)d_in[6];
    const float* b2 = (const float*)d_in[7];

    char* ws = (char*)d_ws;
    size_t off = 0;
    auto alloc = [&](size_t bytes) -> void* {
        void* p = ws + off;
        off += (bytes + 511) & ~(size_t)511;
        return p;
    };
    // zero-region first: deg, cursor, padded recs (pad entries must be {0,0})
    int* deg = (int*)alloc(NN * 4);
    int* cursor = (int*)alloc(NN * 4);
    int2* recs = (int2*)alloc((size_t)NEPAD * 8);
    size_t zbytes = off;
    float* dinv = (float*)alloc(NN * 4);
    int* rp8 = (int*)alloc((NN + 1) * 4);
    int* bsum = (int*)alloc(256 * 4);
    u16* Wt = (u16*)alloc(3 * 128 * 128 * 2);
    u16* hwA = (u16*)alloc((size_t)NN * DIM * 2);
    u16* hwB = (u16*)alloc((size_t)NN * DIM * 2);

    hipMemsetAsync(ws, 0, zbytes, stream);
    k_count<<<NB_E, 256, 0, stream>>>(ei, deg);
    k_scanA<<<NB_N, 256, 0, stream>>>(deg, rp8, bsum);
    k_scanB<<<1, 256, 0, stream>>>(bsum);
    k_scanC<<<NB_N, 256, 0, stream>>>(deg, rp8, bsum, dinv);
    k_fill<<<NB_E, 256, 0, stream>>>(ei, rp8, cursor, dinv, recs);
    k_wcast<<<192, 256, 0, stream>>>(W0, W1, W2, Wt);

    k_gemm_f32<<<(TILES + 3) / 4, 256, 0, stream>>>(x, Wt, hwA);                 // hw1
    k_agg_gemm<<<TILES, 256, 0, stream>>>(hwA, rp8, recs, dinv, b0,
                                          Wt + 16384, hwB);                      // hw2
    k_agg_gemm<<<TILES, 256, 0, stream>>>(hwB, rp8, recs, dinv, b1,
                                          Wt + 32768, hwA);                      // hw3
    k_agg_out<<<NN / 8, 256, 0, stream>>>(hwA, rp8, recs, dinv, b2,
                                          (float*)d_out);
}